// Round 1
// baseline (2485.549 us; speedup 1.0000x reference)
//
#include <hip/hip_runtime.h>
#include <hip/hip_bf16.h>
#include <cstdint>
#include <cstddef>

typedef __attribute__((ext_vector_type(8))) short bf16x8;
typedef __attribute__((ext_vector_type(4))) float f32x4;

constexpr int CW = 32;     // window length
constexpr int CD = 256;    // model dim
constexpr int CH = 8;      // heads
constexpr int CDH = 32;    // head dim
constexpr int CL = 4;      // layers
constexpr int CS = 512;    // seq len

__device__ __forceinline__ short f2bf(float f) {
  union { float f; uint32_t u; } v; v.f = f;
  uint32_t u = v.u;
  uint32_t r = (u + 0x7fffu + ((u >> 16) & 1u)) >> 16;
  return (short)(uint16_t)r;
}

__device__ __forceinline__ f32x4 mfma16(bf16x8 a, bf16x8 b, f32x4 c) {
  return __builtin_amdgcn_mfma_f32_16x16x32_bf16(a, b, c, 0, 0, 0);
}

__global__ void cvt_bf16(const float* __restrict__ src, short* __restrict__ dst, int n) {
  int i = blockIdx.x * blockDim.x + threadIdx.x;
  int stride = gridDim.x * blockDim.x;
  for (; i < n; i += stride) dst[i] = f2bf(src[i]);
}

// B-fragment for mfma_f32_16x16x32_bf16 from a row-major [N][K] weight matrix.
// lane: n = n0 + (lane&15), k = k0 + (lane>>4)*8 + j  (8 contiguous bf16 = 16B)
template<int USEWS>
__device__ __forceinline__ bf16x8 ldB(const short* __restrict__ wb,
                                      const float* __restrict__ wf,
                                      int ldk, int n0, int k0, int lane) {
  int n = n0 + (lane & 15);
  int k = k0 + ((lane >> 4) << 3);
  if constexpr (USEWS) {
    return *(const bf16x8*)&wb[(size_t)n * ldk + k];
  } else {
    const float* p = &wf[(size_t)n * ldk + k];
    f32x4 u = *(const f32x4*)p;
    f32x4 v = *(const f32x4*)(p + 4);
    bf16x8 r;
    r[0]=f2bf(u[0]); r[1]=f2bf(u[1]); r[2]=f2bf(u[2]); r[3]=f2bf(u[3]);
    r[4]=f2bf(v[0]); r[5]=f2bf(v[1]); r[6]=f2bf(v[2]); r[7]=f2bf(v[3]);
    return r;
  }
}

template<int USEWS>
__global__ __launch_bounds__(256, 1)
void swt_fused(const float* __restrict__ X,
               const float* __restrict__ pos,
               const float* __restrict__ wqf, const float* __restrict__ bq_all,
               const float* __restrict__ wof, const float* __restrict__ bo_all,
               const float* __restrict__ w1f, const float* __restrict__ b1_all,
               const float* __restrict__ w2f, const float* __restrict__ b2_all,
               const float* __restrict__ g1_all, const float* __restrict__ be1_all,
               const float* __restrict__ g2_all, const float* __restrict__ be2_all,
               const float* __restrict__ hw, const float* __restrict__ hb,
               const short* __restrict__ wqb, const short* __restrict__ wob,
               const short* __restrict__ w1b, const short* __restrict__ w2b,
               float* __restrict__ out)
{
  __shared__ float xf[CW][CD];          // fp32 residual stream
  __shared__ short xb[CW][CD + 8];      // bf16 copy of x (MFMA A operand)
  __shared__ short qb[CW][CD + 8];      // q (scaled); later attention output o
  __shared__ short kb[CW][CD + 8];      // k; later FFN hidden chunk
  __shared__ short vtb[CH][CDH][40];    // v^T per head: [h][dh][tok]
  __shared__ short pb[CH][CW][40];      // softmax probs per head: [h][q][tok]

  const int tid = threadIdx.x;
  const int wave = tid >> 6;
  const int lane = tid & 63;
  const int lo = lane & 15;
  const int rb4 = (lane >> 4) << 2;     // C-layout row base
  const int k8 = (lane >> 4) << 3;      // A/B-frag k base

  const int blk = blockIdx.x;
  const int bb = blk >> 9;
  const int ss = blk & (CS - 1);

  // ---- Phase 0: build window (slot r holds token clip(s-r,0)) + pos embed ----
  {
    int r = tid >> 3;
    int c0 = (tid & 7) << 5;
    int src = ss - r; if (src < 0) src = 0;
    const float* Xr = X + ((size_t)(bb * CS + src)) * CD + c0;
    const float* Pr = pos + (size_t)r * CD + c0;
    for (int i = 0; i < 32; i += 4) {
      f32x4 xv = *(const f32x4*)(Xr + i);
      f32x4 pv = *(const f32x4*)(Pr + i);
#pragma unroll
      for (int j = 0; j < 4; ++j) {
        float v = xv[j] + pv[j];
        xf[r][c0 + i + j] = v;
        xb[r][c0 + i + j] = f2bf(v);
      }
    }
  }
  __syncthreads();

  const float scale = 0.17677669529663687f;  // 1/sqrt(32)
  bf16x8 a0[8], a1[8];

  auto lnorm = [&](const float* g, const float* be) {
    int r = tid >> 3;
    int c0 = (tid & 7) << 5;
    float s1 = 0.f, s2 = 0.f;
#pragma unroll
    for (int i = 0; i < 32; ++i) { float v = xf[r][c0 + i]; s1 += v; s2 += v * v; }
#pragma unroll
    for (int d = 1; d < 8; d <<= 1) { s1 += __shfl_xor(s1, d); s2 += __shfl_xor(s2, d); }
    float mu = s1 * (1.f / 256.f);
    float var = s2 * (1.f / 256.f) - mu * mu;
    float rs = rsqrtf(var + 1e-5f);
#pragma unroll
    for (int i = 0; i < 32; ++i) {
      int c = c0 + i;
      float v = (xf[r][c] - mu) * rs * g[c] + be[c];
      xf[r][c] = v;
      xb[r][c] = f2bf(v);
    }
  };

  for (int l = 0; l < CL; ++l) {
    // ================= QKV projection: [32,256] x [768,256]^T =================
#pragma unroll
    for (int kk = 0; kk < 8; ++kk) {
      a0[kk] = *(const bf16x8*)&xb[lo][kk * 32 + k8];
      a1[kk] = *(const bf16x8*)&xb[16 + lo][kk * 32 + k8];
    }
    {
      const short* wb = wqb + (size_t)l * 768 * 256;
      const float* wf = wqf + (size_t)l * 768 * 256;
      const float* bias = bq_all + l * 768;
#pragma unroll 1
      for (int tp = 0; tp < 6; ++tp) {
        int n0 = (wave * 12 + tp * 2) * 16;
        int n1 = n0 + 16;
        f32x4 c00 = {0.f,0.f,0.f,0.f}, c01 = c00, c10 = c00, c11 = c00;
#pragma unroll
        for (int kk = 0; kk < 8; ++kk) {
          bf16x8 b0  = ldB<USEWS>(wb, wf, 256, n0, kk * 32, lane);
          bf16x8 b1v = ldB<USEWS>(wb, wf, 256, n1, kk * 32, lane);
          c00 = mfma16(a0[kk], b0,  c00);
          c10 = mfma16(a1[kk], b0,  c10);
          c01 = mfma16(a0[kk], b1v, c01);
          c11 = mfma16(a1[kk], b1v, c11);
        }
#pragma unroll
        for (int half = 0; half < 2; ++half) {
          int nn = half ? n1 : n0;
          f32x4 u0 = half ? c01 : c00;
          f32x4 u1 = half ? c11 : c10;
          int col = nn + lo;
          float bv = bias[col];
#pragma unroll
          for (int j = 0; j < 4; ++j) {
            float v0 = u0[j] + bv;
            float v1 = u1[j] + bv;
            int r0 = rb4 + j, r1 = rb4 + j + 16;
            if (nn < 256) {               // q (pre-scaled)
              qb[r0][col] = f2bf(v0 * scale);
              qb[r1][col] = f2bf(v1 * scale);
            } else if (nn < 512) {        // k
              kb[r0][col - 256] = f2bf(v0);
              kb[r1][col - 256] = f2bf(v1);
            } else {                      // v, stored transposed per head
              int h = (col - 512) >> 5, dh = (col - 512) & 31;
              vtb[h][dh][r0] = f2bf(v0);
              vtb[h][dh][r1] = f2bf(v1);
            }
          }
        }
      }
    }
    __syncthreads();

    // ================= attention: 2 heads per wave =================
#pragma unroll 1
    for (int hi = 0; hi < 2; ++hi) {
      int h = wave * 2 + hi;
      int hc = h * 32;
      f32x4 sc[2][2];
#pragma unroll
      for (int mt = 0; mt < 2; ++mt) {
        bf16x8 aq = *(const bf16x8*)&qb[mt * 16 + lo][hc + k8];
#pragma unroll
        for (int nt = 0; nt < 2; ++nt) {
          bf16x8 bk = *(const bf16x8*)&kb[nt * 16 + lo][hc + k8];
          f32x4 z = {0.f,0.f,0.f,0.f};
          sc[mt][nt] = mfma16(aq, bk, z);
        }
      }
      // softmax over 32 keys: values live across 16 lanes x 2 n-tiles
#pragma unroll
      for (int mt = 0; mt < 2; ++mt) {
#pragma unroll
        for (int j = 0; j < 4; ++j) {
          float v0 = sc[mt][0][j], v1 = sc[mt][1][j];
          float m = fmaxf(v0, v1);
#pragma unroll
          for (int d = 1; d < 16; d <<= 1) m = fmaxf(m, __shfl_xor(m, d));
          float p0 = __expf(v0 - m), p1 = __expf(v1 - m);
          float sm = p0 + p1;
#pragma unroll
          for (int d = 1; d < 16; d <<= 1) sm += __shfl_xor(sm, d);
          float inv = 1.0f / sm;
          int row = mt * 16 + rb4 + j;
          pb[h][row][lo]      = f2bf(p0 * inv);
          pb[h][row][16 + lo] = f2bf(p1 * inv);
        }
      }
      asm volatile("s_waitcnt lgkmcnt(0)" ::: "memory");  // own-wave pb writes visible
      // PV: o[q][dh] = P @ v  (B operand from v^T, contiguous in tok)
#pragma unroll
      for (int mt = 0; mt < 2; ++mt) {
        bf16x8 ap = *(const bf16x8*)&pb[h][mt * 16 + lo][k8];
#pragma unroll
        for (int dt = 0; dt < 2; ++dt) {
          bf16x8 bv = *(const bf16x8*)&vtb[h][dt * 16 + lo][k8];
          f32x4 z = {0.f,0.f,0.f,0.f};
          f32x4 o = mfma16(ap, bv, z);
          int col = hc + dt * 16 + lo;   // own head's columns only (disjoint from next head's q)
#pragma unroll
          for (int j = 0; j < 4; ++j)
            qb[mt * 16 + rb4 + j][col] = f2bf(o[j]);
        }
      }
    }
    __syncthreads();

    // ================= output projection + residual =================
#pragma unroll
    for (int kk = 0; kk < 8; ++kk) {
      a0[kk] = *(const bf16x8*)&qb[lo][kk * 32 + k8];
      a1[kk] = *(const bf16x8*)&qb[16 + lo][kk * 32 + k8];
    }
    {
      const short* wb = wob + (size_t)l * 256 * 256;
      const float* wf = wof + (size_t)l * 256 * 256;
      const float* bias = bo_all + l * 256;
#pragma unroll 1
      for (int tp = 0; tp < 2; ++tp) {
        int n0 = (wave * 4 + tp * 2) * 16;
        int n1 = n0 + 16;
        f32x4 c00 = {0.f,0.f,0.f,0.f}, c01 = c00, c10 = c00, c11 = c00;
#pragma unroll
        for (int kk = 0; kk < 8; ++kk) {
          bf16x8 b0  = ldB<USEWS>(wb, wf, 256, n0, kk * 32, lane);
          bf16x8 b1v = ldB<USEWS>(wb, wf, 256, n1, kk * 32, lane);
          c00 = mfma16(a0[kk], b0,  c00);
          c10 = mfma16(a1[kk], b0,  c10);
          c01 = mfma16(a0[kk], b1v, c01);
          c11 = mfma16(a1[kk], b1v, c11);
        }
#pragma unroll
        for (int half = 0; half < 2; ++half) {
          int nn = half ? n1 : n0;
          f32x4 u0 = half ? c01 : c00;
          f32x4 u1 = half ? c11 : c10;
          int col = nn + lo;
          float bv = bias[col];
#pragma unroll
          for (int j = 0; j < 4; ++j) {
            xf[rb4 + j][col]      += u0[j] + bv;
            xf[rb4 + j + 16][col] += u1[j] + bv;
          }
        }
      }
    }
    __syncthreads();
    lnorm(g1_all + l * 256, be1_all + l * 256);
    __syncthreads();

    // ================= FFN: relu(x W1^T) W2^T, 4 chunks of 256 =================
#pragma unroll
    for (int kk = 0; kk < 8; ++kk) {
      a0[kk] = *(const bf16x8*)&xb[lo][kk * 32 + k8];
      a1[kk] = *(const bf16x8*)&xb[16 + lo][kk * 32 + k8];
    }
    {
      const short* w1bl = w1b + (size_t)l * 1024 * 256;
      const float* w1fl = w1f + (size_t)l * 1024 * 256;
      const float* bias1 = b1_all + l * 1024;
      const short* w2bl = w2b + (size_t)l * 256 * 1024;
      const float* w2fl = w2f + (size_t)l * 256 * 1024;
      f32x4 fa[2][2][2];
#pragma unroll
      for (int i = 0; i < 2; ++i)
#pragma unroll
        for (int j2 = 0; j2 < 2; ++j2)
#pragma unroll
          for (int m = 0; m < 2; ++m) fa[i][j2][m] = {0.f,0.f,0.f,0.f};

#pragma unroll 1
      for (int ch = 0; ch < 4; ++ch) {
        // FFN1 chunk -> kb (relu'd, bf16)
#pragma unroll 1
        for (int tp = 0; tp < 2; ++tp) {
          int nl0 = (wave * 4 + tp * 2) * 16;
          int nl1 = nl0 + 16;
          int ng0 = ch * 256 + nl0, ng1 = ng0 + 16;
          f32x4 c00 = {0.f,0.f,0.f,0.f}, c01 = c00, c10 = c00, c11 = c00;
#pragma unroll
          for (int kk = 0; kk < 8; ++kk) {
            bf16x8 b0  = ldB<USEWS>(w1bl, w1fl, 256, ng0, kk * 32, lane);
            bf16x8 b1v = ldB<USEWS>(w1bl, w1fl, 256, ng1, kk * 32, lane);
            c00 = mfma16(a0[kk], b0,  c00);
            c10 = mfma16(a1[kk], b0,  c10);
            c01 = mfma16(a0[kk], b1v, c01);
            c11 = mfma16(a1[kk], b1v, c11);
          }
#pragma unroll
          for (int half = 0; half < 2; ++half) {
            int nl = half ? nl1 : nl0;
            int ng = half ? ng1 : ng0;
            f32x4 u0 = half ? c01 : c00;
            f32x4 u1 = half ? c11 : c10;
            int colL = nl + lo;
            float bv = bias1[ng + lo];
#pragma unroll
            for (int j = 0; j < 4; ++j) {
              kb[rb4 + j][colL]      = f2bf(fmaxf(u0[j] + bv, 0.f));
              kb[rb4 + j + 16][colL] = f2bf(fmaxf(u1[j] + bv, 0.f));
            }
          }
        }
        __syncthreads();
        // FFN2 partial over this K-chunk, accumulate in registers
#pragma unroll
        for (int kk = 0; kk < 8; ++kk) {
          bf16x8 h0 = *(const bf16x8*)&kb[lo][kk * 32 + k8];
          bf16x8 h1 = *(const bf16x8*)&kb[16 + lo][kk * 32 + k8];
          int kg = ch * 256 + kk * 32;
#pragma unroll
          for (int tp = 0; tp < 2; ++tp) {
            int n0 = (wave * 4 + tp * 2) * 16;
            int n1 = n0 + 16;
            bf16x8 b0  = ldB<USEWS>(w2bl, w2fl, 1024, n0, kg, lane);
            bf16x8 b1v = ldB<USEWS>(w2bl, w2fl, 1024, n1, kg, lane);
            fa[tp][0][0] = mfma16(h0, b0,  fa[tp][0][0]);
            fa[tp][0][1] = mfma16(h1, b0,  fa[tp][0][1]);
            fa[tp][1][0] = mfma16(h0, b1v, fa[tp][1][0]);
            fa[tp][1][1] = mfma16(h1, b1v, fa[tp][1][1]);
          }
        }
        __syncthreads();
      }
      // FFN2 epilogue: bias + residual into xf
      const float* bias2 = b2_all + l * 256;
#pragma unroll
      for (int tp = 0; tp < 2; ++tp) {
#pragma unroll
        for (int nn = 0; nn < 2; ++nn) {
          int col = (wave * 4 + tp * 2 + nn) * 16 + lo;
          float bv = bias2[col];
#pragma unroll
          for (int j = 0; j < 4; ++j) {
            xf[rb4 + j][col]      += fa[tp][nn][0][j] + bv;
            xf[rb4 + j + 16][col] += fa[tp][nn][1][j] + bv;
          }
        }
      }
    }
    __syncthreads();
    lnorm(g2_all + l * 256, be2_all + l * 256);
    __syncthreads();
  }

  // ================= head: logits = x[slot 31] @ head_w^T + head_b =================
  {
    int c = tid >> 3;        // 0..31 output
    int p = tid & 7;         // 8-way K split
    float sum = 0.f;
#pragma unroll
    for (int i = 0; i < 32; ++i) {
      int k = (p << 5) + i;
      sum += xf[31][k] * hw[c * 256 + k];
    }
#pragma unroll
    for (int d = 1; d < 8; d <<= 1) sum += __shfl_xor(sum, d);
    if (p == 0) out[(size_t)blk * 32 + c] = sum + hb[c];
  }
}

extern "C" void kernel_launch(void* const* d_in, const int* in_sizes, int n_in,
                              void* d_out, int out_size, void* d_ws, size_t ws_size,
                              hipStream_t stream) {
  const float* X    = (const float*)d_in[0];
  // d_in[1] action_seq, d_in[2] mask: unused by the reference
  const float* pos  = (const float*)d_in[3];
  const float* wq   = (const float*)d_in[4];
  const float* bq   = (const float*)d_in[5];
  const float* wo   = (const float*)d_in[6];
  const float* bo   = (const float*)d_in[7];
  const float* w1   = (const float*)d_in[8];
  const float* b1   = (const float*)d_in[9];
  const float* w2   = (const float*)d_in[10];
  const float* b2   = (const float*)d_in[11];
  const float* g1   = (const float*)d_in[12];
  const float* be1  = (const float*)d_in[13];
  const float* g2   = (const float*)d_in[14];
  const float* be2  = (const float*)d_in[15];
  const float* hw   = (const float*)d_in[16];
  const float* hb   = (const float*)d_in[17];
  float* out = (float*)d_out;

  const size_t nq = (size_t)CL * 768 * 256;
  const size_t no = (size_t)CL * 256 * 256;
  const size_t n1 = (size_t)CL * 1024 * 256;
  const size_t n2 = (size_t)CL * 256 * 1024;
  const size_t need = (nq + no + n1 + n2) * sizeof(short);

  short* wsq = (short*)d_ws;
  short* wso = wsq + nq;
  short* ws1 = wso + no;
  short* ws2 = ws1 + n1;

  const int nblk = 4 * 512;  // B*S windows

  if (ws_size >= need) {
    cvt_bf16<<<512, 256, 0, stream>>>(wq, wsq, (int)nq);
    cvt_bf16<<<512, 256, 0, stream>>>(wo, wso, (int)no);
    cvt_bf16<<<512, 256, 0, stream>>>(w1, ws1, (int)n1);
    cvt_bf16<<<512, 256, 0, stream>>>(w2, ws2, (int)n2);
    swt_fused<1><<<nblk, 256, 0, stream>>>(X, pos, wq, bq, wo, bo, w1, b1, w2, b2,
                                           g1, be1, g2, be2, hw, hb,
                                           wsq, wso, ws1, ws2, out);
  } else {
    swt_fused<0><<<nblk, 256, 0, stream>>>(X, pos, wq, bq, wo, bo, w1, b1, w2, b2,
                                           g1, be1, g2, be2, hw, hb,
                                           nullptr, nullptr, nullptr, nullptr, out);
  }
}

// Round 2
// 2030.690 us; speedup vs baseline: 1.2240x; 1.2240x over previous
//
#include <hip/hip_runtime.h>
#include <hip/hip_bf16.h>
#include <cstdint>
#include <cstddef>

typedef __attribute__((ext_vector_type(8))) short bf16x8;
typedef __attribute__((ext_vector_type(4))) float f32x4;

constexpr int CW = 32;     // window length
constexpr int CD = 256;    // model dim
constexpr int CH = 8;      // heads
constexpr int CL = 4;      // layers
constexpr int CS = 512;    // seq len
constexpr int XFS = 260;   // xf row stride (floats) - breaks pow2 bank pattern

__device__ __forceinline__ short f2bf(float f) {
  union { float f; uint32_t u; } v; v.f = f;
  uint32_t u = v.u;
  uint32_t r = (u + 0x7fffu + ((u >> 16) & 1u)) >> 16;
  return (short)(uint16_t)r;
}

__device__ __forceinline__ f32x4 mfma16(bf16x8 a, bf16x8 b, f32x4 c) {
  return __builtin_amdgcn_mfma_f32_16x16x32_bf16(a, b, c, 0, 0, 0);
}

// XOR bank swizzle for [32][256] bf16 LDS tiles, 16B granule
__device__ __forceinline__ int swz8(int row, int col) {   // col 8-aligned
  return row * 256 + ((((col >> 3) ^ (row & 7)) << 3));
}
__device__ __forceinline__ int swzi(int row, int col) {   // arbitrary col
  return row * 256 + (((((col >> 3) ^ (row & 7)) << 3)) | (col & 7));
}

__global__ void cvt_bf16(const float* __restrict__ src, short* __restrict__ dst, int n) {
  int i = blockIdx.x * blockDim.x + threadIdx.x;
  int stride = gridDim.x * blockDim.x;
  for (; i < n; i += stride) dst[i] = f2bf(src[i]);
}

// B-fragment for mfma_f32_16x16x32_bf16 from a row-major [N][K] weight matrix.
template<int USEWS>
__device__ __forceinline__ bf16x8 ldB(const short* __restrict__ wb,
                                      const float* __restrict__ wf,
                                      int ldk, int n0, int k0, int lane) {
  int n = n0 + (lane & 15);
  int k = k0 + ((lane >> 4) << 3);
  if constexpr (USEWS) {
    return *(const bf16x8*)&wb[(size_t)n * ldk + k];
  } else {
    const float* p = &wf[(size_t)n * ldk + k];
    f32x4 u = *(const f32x4*)p;
    f32x4 v = *(const f32x4*)(p + 4);
    bf16x8 r;
    r[0]=f2bf(u[0]); r[1]=f2bf(u[1]); r[2]=f2bf(u[2]); r[3]=f2bf(u[3]);
    r[4]=f2bf(v[0]); r[5]=f2bf(v[1]); r[6]=f2bf(v[2]); r[7]=f2bf(v[3]);
    return r;
  }
}

template<int USEWS>
__global__ __launch_bounds__(512, 2)
void swt_fused(const float* __restrict__ X,
               const float* __restrict__ pos,
               const float* __restrict__ wqf, const float* __restrict__ bq_all,
               const float* __restrict__ wof, const float* __restrict__ bo_all,
               const float* __restrict__ w1f, const float* __restrict__ b1_all,
               const float* __restrict__ w2f, const float* __restrict__ b2_all,
               const float* __restrict__ g1_all, const float* __restrict__ be1_all,
               const float* __restrict__ g2_all, const float* __restrict__ be2_all,
               const float* __restrict__ hw, const float* __restrict__ hb,
               const short* __restrict__ wqb, const short* __restrict__ wob,
               const short* __restrict__ w1b, const short* __restrict__ w2b,
               float* __restrict__ out)
{
  __shared__ float xf[CW * XFS];        // fp32 residual stream
  __shared__ short xb[CW * 256];        // bf16 x (swizzled)
  __shared__ short qb[CW * 256];        // q -> attention output o (swizzled)
  __shared__ short kb[CW * 256];        // k -> FFN hidden chunk (swizzled)
  __shared__ short vtb[CH][32][40];     // v^T per head: [h][dh][tok]
  __shared__ short pb[CH][CW][40];      // softmax probs: [h][q][tok]

  const int tid = threadIdx.x;
  const int wave = tid >> 6;
  const int lane = tid & 63;
  const int lo = lane & 15;
  const int rb4 = (lane >> 4) << 2;     // C-layout row base
  const int k8 = (lane >> 4) << 3;      // A/B-frag k base

  const int blk = blockIdx.x;
  const int bb = blk >> 9;
  const int ss = blk & (CS - 1);

  // ---- Phase 0: build window (slot r = token clip(s-r,0)) + pos embed ----
  {
    int r = tid >> 4;
    int c0 = (tid & 15) << 4;
    int src = ss - r; if (src < 0) src = 0;
    const float* Xr = X + ((size_t)(bb * CS + src)) * CD + c0;
    const float* Pr = pos + (size_t)r * CD + c0;
#pragma unroll
    for (int m = 0; m < 2; ++m) {
      f32x4 x0 = *(const f32x4*)(Xr + m * 8);
      f32x4 x1 = *(const f32x4*)(Xr + m * 8 + 4);
      f32x4 p0 = *(const f32x4*)(Pr + m * 8);
      f32x4 p1 = *(const f32x4*)(Pr + m * 8 + 4);
      bf16x8 pk;
#pragma unroll
      for (int j = 0; j < 4; ++j) {
        float v = x0[j] + p0[j];
        xf[r * XFS + c0 + m * 8 + j] = v;
        pk[j] = f2bf(v);
      }
#pragma unroll
      for (int j = 0; j < 4; ++j) {
        float v = x1[j] + p1[j];
        xf[r * XFS + c0 + m * 8 + 4 + j] = v;
        pk[4 + j] = f2bf(v);
      }
      *(bf16x8*)&xb[swz8(r, c0 + m * 8)] = pk;
    }
  }
  __syncthreads();

  const float scale = 0.17677669529663687f;  // 1/sqrt(32)

  auto lnorm = [&](const float* g, const float* be) {
    int r = tid >> 4;
    int p = tid & 15;
    float* xr = xf + r * XFS;
    float s1 = 0.f, s2 = 0.f;
#pragma unroll
    for (int i = 0; i < 16; ++i) { float v = xr[p + (i << 4)]; s1 += v; s2 += v * v; }
#pragma unroll
    for (int d = 1; d < 16; d <<= 1) { s1 += __shfl_xor(s1, d); s2 += __shfl_xor(s2, d); }
    float mu = s1 * (1.f / 256.f);
    float var = s2 * (1.f / 256.f) - mu * mu;
    float rs = rsqrtf(var + 1e-5f);
#pragma unroll
    for (int i = 0; i < 8; ++i) {
      int c = (p << 1) + (i << 5);
      float v0 = (xr[c] - mu) * rs * g[c] + be[c];
      float v1 = (xr[c + 1] - mu) * rs * g[c + 1] + be[c + 1];
      xr[c] = v0;
      xr[c + 1] = v1;
      uint32_t pk2 = (uint32_t)(uint16_t)f2bf(v0) | ((uint32_t)(uint16_t)f2bf(v1) << 16);
      *(uint32_t*)&xb[swzi(r, c)] = pk2;
    }
  };

#pragma unroll 1
  for (int l = 0; l < CL; ++l) {
    bf16x8 a0[8], a1[8];
    // ================= QKV projection: [32,256] x [768,256]^T =================
#pragma unroll
    for (int kk = 0; kk < 8; ++kk) {
      a0[kk] = *(const bf16x8*)&xb[swz8(lo, kk * 32 + k8)];
      a1[kk] = *(const bf16x8*)&xb[swz8(16 + lo, kk * 32 + k8)];
    }
    {
      const short* wb = wqb + (size_t)l * 768 * 256;
      const float* wf = wqf + (size_t)l * 768 * 256;
      const float* bias = bq_all + l * 768;
      for (int tp = 0; tp < 3; ++tp) {
        int n0 = wave * 96 + tp * 32;
        int n1 = n0 + 16;
        f32x4 c00 = {0.f,0.f,0.f,0.f}, c01 = c00, c10 = c00, c11 = c00;
#pragma unroll
        for (int kk = 0; kk < 8; ++kk) {
          bf16x8 b0  = ldB<USEWS>(wb, wf, 256, n0, kk * 32, lane);
          bf16x8 b1v = ldB<USEWS>(wb, wf, 256, n1, kk * 32, lane);
          c00 = mfma16(a0[kk], b0,  c00);
          c10 = mfma16(a1[kk], b0,  c10);
          c01 = mfma16(a0[kk], b1v, c01);
          c11 = mfma16(a1[kk], b1v, c11);
        }
#pragma unroll
        for (int half = 0; half < 2; ++half) {
          int nn = half ? n1 : n0;
          f32x4 u0 = half ? c01 : c00;
          f32x4 u1 = half ? c11 : c10;
          int col = nn + lo;
          float bv = bias[col];
#pragma unroll
          for (int j = 0; j < 4; ++j) {
            float v0 = u0[j] + bv;
            float v1 = u1[j] + bv;
            int r0 = rb4 + j, r1 = rb4 + j + 16;
            if (nn < 256) {               // q (pre-scaled)
              qb[swzi(r0, col)] = f2bf(v0 * scale);
              qb[swzi(r1, col)] = f2bf(v1 * scale);
            } else if (nn < 512) {        // k
              kb[swzi(r0, col - 256)] = f2bf(v0);
              kb[swzi(r1, col - 256)] = f2bf(v1);
            } else {                      // v, transposed per head
              int h = (col - 512) >> 5, dh = (col - 512) & 31;
              vtb[h][dh][r0] = f2bf(v0);
              vtb[h][dh][r1] = f2bf(v1);
            }
          }
        }
      }
    }
    __syncthreads();

    // ================= attention: 1 head per wave =================
    {
      int h = wave;
      int hc = h * 32;
      f32x4 sc[2][2];
#pragma unroll
      for (int mt = 0; mt < 2; ++mt) {
        bf16x8 aq = *(const bf16x8*)&qb[swz8(mt * 16 + lo, hc + k8)];
#pragma unroll
        for (int nt = 0; nt < 2; ++nt) {
          bf16x8 bk = *(const bf16x8*)&kb[swz8(nt * 16 + lo, hc + k8)];
          f32x4 z = {0.f,0.f,0.f,0.f};
          sc[mt][nt] = mfma16(aq, bk, z);
        }
      }
#pragma unroll
      for (int mt = 0; mt < 2; ++mt) {
#pragma unroll
        for (int j = 0; j < 4; ++j) {
          float v0 = sc[mt][0][j], v1 = sc[mt][1][j];
          float m = fmaxf(v0, v1);
#pragma unroll
          for (int d = 1; d < 16; d <<= 1) m = fmaxf(m, __shfl_xor(m, d));
          float p0 = __expf(v0 - m), p1 = __expf(v1 - m);
          float sm = p0 + p1;
#pragma unroll
          for (int d = 1; d < 16; d <<= 1) sm += __shfl_xor(sm, d);
          float inv = 1.0f / sm;
          int row = mt * 16 + rb4 + j;
          pb[h][row][lo]      = f2bf(p0 * inv);
          pb[h][row][16 + lo] = f2bf(p1 * inv);
        }
      }
      asm volatile("s_waitcnt lgkmcnt(0)" ::: "memory");
      __builtin_amdgcn_sched_barrier(0);
      // PV: o[q][dh] = P @ v
#pragma unroll
      for (int mt = 0; mt < 2; ++mt) {
        bf16x8 ap = *(const bf16x8*)&pb[h][mt * 16 + lo][k8];
#pragma unroll
        for (int dt = 0; dt < 2; ++dt) {
          bf16x8 bv = *(const bf16x8*)&vtb[h][dt * 16 + lo][k8];
          f32x4 z = {0.f,0.f,0.f,0.f};
          f32x4 o = mfma16(ap, bv, z);
#pragma unroll
          for (int j = 0; j < 4; ++j)
            qb[swzi(mt * 16 + rb4 + j, hc + dt * 16 + lo)] = f2bf(o[j]);
        }
      }
    }
    __syncthreads();

    // ================= output projection + residual =================
#pragma unroll
    for (int kk = 0; kk < 8; ++kk) {
      a0[kk] = *(const bf16x8*)&qb[swz8(lo, kk * 32 + k8)];
      a1[kk] = *(const bf16x8*)&qb[swz8(16 + lo, kk * 32 + k8)];
    }
    {
      const short* wb = wob + (size_t)l * 256 * 256;
      const float* wf = wof + (size_t)l * 256 * 256;
      const float* bias = bo_all + l * 256;
      int n0 = wave * 32;
      int n1 = n0 + 16;
      f32x4 c00 = {0.f,0.f,0.f,0.f}, c01 = c00, c10 = c00, c11 = c00;
#pragma unroll
      for (int kk = 0; kk < 8; ++kk) {
        bf16x8 b0  = ldB<USEWS>(wb, wf, 256, n0, kk * 32, lane);
        bf16x8 b1v = ldB<USEWS>(wb, wf, 256, n1, kk * 32, lane);
        c00 = mfma16(a0[kk], b0,  c00);
        c10 = mfma16(a1[kk], b0,  c10);
        c01 = mfma16(a0[kk], b1v, c01);
        c11 = mfma16(a1[kk], b1v, c11);
      }
#pragma unroll
      for (int half = 0; half < 2; ++half) {
        int nn = half ? n1 : n0;
        f32x4 u0 = half ? c01 : c00;
        f32x4 u1 = half ? c11 : c10;
        int col = nn + lo;
        float bv = bias[col];
#pragma unroll
        for (int j = 0; j < 4; ++j) {
          xf[(rb4 + j) * XFS + col]      += u0[j] + bv;
          xf[(rb4 + j + 16) * XFS + col] += u1[j] + bv;
        }
      }
    }
    __syncthreads();
    lnorm(g1_all + l * 256, be1_all + l * 256);
    __syncthreads();

    // ================= FFN: relu(x W1^T) W2^T, 4 chunks of 256 =================
#pragma unroll
    for (int kk = 0; kk < 8; ++kk) {
      a0[kk] = *(const bf16x8*)&xb[swz8(lo, kk * 32 + k8)];
      a1[kk] = *(const bf16x8*)&xb[swz8(16 + lo, kk * 32 + k8)];
    }
    {
      const short* w1bl = w1b + (size_t)l * 1024 * 256;
      const float* w1fl = w1f + (size_t)l * 1024 * 256;
      const float* bias1 = b1_all + l * 1024;
      const short* w2bl = w2b + (size_t)l * 256 * 1024;
      const float* w2fl = w2f + (size_t)l * 256 * 1024;
      f32x4 fa[2][2];
#pragma unroll
      for (int nt = 0; nt < 2; ++nt)
#pragma unroll
        for (int m = 0; m < 2; ++m) fa[nt][m] = {0.f,0.f,0.f,0.f};

#pragma unroll 1
      for (int ch = 0; ch < 4; ++ch) {
        int nl0 = wave * 32;
        int nl1 = nl0 + 16;
        int ng0 = ch * 256 + nl0, ng1 = ng0 + 16;
        f32x4 c00 = {0.f,0.f,0.f,0.f}, c01 = c00, c10 = c00, c11 = c00;
#pragma unroll
        for (int kk = 0; kk < 8; ++kk) {
          bf16x8 b0  = ldB<USEWS>(w1bl, w1fl, 256, ng0, kk * 32, lane);
          bf16x8 b1v = ldB<USEWS>(w1bl, w1fl, 256, ng1, kk * 32, lane);
          c00 = mfma16(a0[kk], b0,  c00);
          c10 = mfma16(a1[kk], b0,  c10);
          c01 = mfma16(a0[kk], b1v, c01);
          c11 = mfma16(a1[kk], b1v, c11);
        }
#pragma unroll
        for (int half = 0; half < 2; ++half) {
          int nl = half ? nl1 : nl0;
          int ng = half ? ng1 : ng0;
          f32x4 u0 = half ? c01 : c00;
          f32x4 u1 = half ? c11 : c10;
          int colL = nl + lo;
          float bv = bias1[ng + lo];
#pragma unroll
          for (int j = 0; j < 4; ++j) {
            kb[swzi(rb4 + j, colL)]      = f2bf(fmaxf(u0[j] + bv, 0.f));
            kb[swzi(rb4 + j + 16, colL)] = f2bf(fmaxf(u1[j] + bv, 0.f));
          }
        }
        __syncthreads();
        // FFN2 partial over this K-chunk
#pragma unroll
        for (int kk = 0; kk < 8; ++kk) {
          bf16x8 h0 = *(const bf16x8*)&kb[swz8(lo, kk * 32 + k8)];
          bf16x8 h1 = *(const bf16x8*)&kb[swz8(16 + lo, kk * 32 + k8)];
          int kg = ch * 256 + kk * 32;
          int n0 = wave * 32;
          int n1 = n0 + 16;
          bf16x8 b0  = ldB<USEWS>(w2bl, w2fl, 1024, n0, kg, lane);
          bf16x8 b1v = ldB<USEWS>(w2bl, w2fl, 1024, n1, kg, lane);
          fa[0][0] = mfma16(h0, b0,  fa[0][0]);
          fa[0][1] = mfma16(h1, b0,  fa[0][1]);
          fa[1][0] = mfma16(h0, b1v, fa[1][0]);
          fa[1][1] = mfma16(h1, b1v, fa[1][1]);
        }
        __syncthreads();
      }
      // FFN2 epilogue: bias + residual
      const float* bias2 = b2_all + l * 256;
#pragma unroll
      for (int nt = 0; nt < 2; ++nt) {
        int col = wave * 32 + nt * 16 + lo;
        float bv = bias2[col];
#pragma unroll
        for (int j = 0; j < 4; ++j) {
          xf[(rb4 + j) * XFS + col]      += fa[nt][0][j] + bv;
          xf[(rb4 + j + 16) * XFS + col] += fa[nt][1][j] + bv;
        }
      }
    }
    __syncthreads();
    lnorm(g2_all + l * 256, be2_all + l * 256);
    __syncthreads();
  }

  // ================= head: logits = x[slot 31] @ head_w^T + head_b =================
  {
    int c = tid >> 4;        // 0..31 output
    int p = tid & 15;        // 16-way K split
    float sum = 0.f;
#pragma unroll
    for (int i = 0; i < 16; ++i) {
      int k = p + (i << 4);
      sum += xf[31 * XFS + k] * hw[c * 256 + k];
    }
#pragma unroll
    for (int d = 1; d < 16; d <<= 1) sum += __shfl_xor(sum, d);
    if (p == 0) out[(size_t)blk * 32 + c] = sum + hb[c];
  }
}

extern "C" void kernel_launch(void* const* d_in, const int* in_sizes, int n_in,
                              void* d_out, int out_size, void* d_ws, size_t ws_size,
                              hipStream_t stream) {
  const float* X    = (const float*)d_in[0];
  const float* pos  = (const float*)d_in[3];
  const float* wq   = (const float*)d_in[4];
  const float* bq   = (const float*)d_in[5];
  const float* wo   = (const float*)d_in[6];
  const float* bo   = (const float*)d_in[7];
  const float* w1   = (const float*)d_in[8];
  const float* b1   = (const float*)d_in[9];
  const float* w2   = (const float*)d_in[10];
  const float* b2   = (const float*)d_in[11];
  const float* g1   = (const float*)d_in[12];
  const float* be1  = (const float*)d_in[13];
  const float* g2   = (const float*)d_in[14];
  const float* be2  = (const float*)d_in[15];
  const float* hw   = (const float*)d_in[16];
  const float* hb   = (const float*)d_in[17];
  float* out = (float*)d_out;

  const size_t nq = (size_t)CL * 768 * 256;
  const size_t no = (size_t)CL * 256 * 256;
  const size_t n1 = (size_t)CL * 1024 * 256;
  const size_t n2 = (size_t)CL * 256 * 1024;
  const size_t need = (nq + no + n1 + n2) * sizeof(short);

  short* wsq = (short*)d_ws;
  short* wso = wsq + nq;
  short* ws1 = wso + no;
  short* ws2 = ws1 + n1;

  const int nblk = 4 * 512;

  if (ws_size >= need) {
    cvt_bf16<<<512, 256, 0, stream>>>(wq, wsq, (int)nq);
    cvt_bf16<<<512, 256, 0, stream>>>(wo, wso, (int)no);
    cvt_bf16<<<512, 256, 0, stream>>>(w1, ws1, (int)n1);
    cvt_bf16<<<512, 256, 0, stream>>>(w2, ws2, (int)n2);
    swt_fused<1><<<nblk, 512, 0, stream>>>(X, pos, wq, bq, wo, bo, w1, b1, w2, b2,
                                           g1, be1, g2, be2, hw, hb,
                                           wsq, wso, ws1, ws2, out);
  } else {
    swt_fused<0><<<nblk, 512, 0, stream>>>(X, pos, wq, bq, wo, bo, w1, b1, w2, b2,
                                           g1, be1, g2, be2, hw, hb,
                                           nullptr, nullptr, nullptr, nullptr, out);
  }
}

// Round 3
// 1695.068 us; speedup vs baseline: 1.4663x; 1.1980x over previous
//
#include <hip/hip_runtime.h>
#include <hip/hip_bf16.h>
#include <cstdint>
#include <cstddef>

typedef __attribute__((ext_vector_type(8))) short bf16x8;
typedef __attribute__((ext_vector_type(4))) float f32x4;

constexpr int CW = 32;     // window length
constexpr int CD = 256;    // model dim
constexpr int CH = 8;      // heads
constexpr int CL = 4;      // layers
constexpr int CS = 512;    // seq len
constexpr int XFS = 260;   // xf row stride (floats)

__device__ __forceinline__ short f2bf(float f) {
  union { float f; uint32_t u; } v; v.f = f;
  uint32_t u = v.u;
  uint32_t r = (u + 0x7fffu + ((u >> 16) & 1u)) >> 16;
  return (short)(uint16_t)r;
}

__device__ __forceinline__ f32x4 mfma16(bf16x8 a, bf16x8 b, f32x4 c) {
  return __builtin_amdgcn_mfma_f32_16x16x32_bf16(a, b, c, 0, 0, 0);
}

// XOR bank swizzle for [32][256] bf16 LDS tiles, 16B granule
__device__ __forceinline__ int swz8(int row, int col) {   // col 8-aligned
  return row * 256 + ((((col >> 3) ^ (row & 7)) << 3));
}
__device__ __forceinline__ int swzi(int row, int col) {   // arbitrary col
  return row * 256 + (((((col >> 3) ^ (row & 7)) << 3)) | (col & 7));
}

__global__ void cvt_bf16(const float* __restrict__ src, short* __restrict__ dst, int n) {
  int i = blockIdx.x * blockDim.x + threadIdx.x;
  int stride = gridDim.x * blockDim.x;
  for (; i < n; i += stride) dst[i] = f2bf(src[i]);
}

// B-fragment for mfma_f32_16x16x32_bf16 from a row-major [N][K] weight matrix.
template<int USEWS>
__device__ __forceinline__ bf16x8 ldB(const short* __restrict__ wb,
                                      const float* __restrict__ wf,
                                      int ldk, int n0, int k0, int lane) {
  int n = n0 + (lane & 15);
  int k = k0 + ((lane >> 4) << 3);
  if constexpr (USEWS) {
    return *(const bf16x8*)&wb[(size_t)n * ldk + k];
  } else {
    const float* p = &wf[(size_t)n * ldk + k];
    f32x4 u = *(const f32x4*)p;
    f32x4 v = *(const f32x4*)(p + 4);
    bf16x8 r;
    r[0]=f2bf(u[0]); r[1]=f2bf(u[1]); r[2]=f2bf(u[2]); r[3]=f2bf(u[3]);
    r[4]=f2bf(v[0]); r[5]=f2bf(v[1]); r[6]=f2bf(v[2]); r[7]=f2bf(v[3]);
    return r;
  }
}

template<int USEWS>
__global__ __launch_bounds__(1024, 1)
void swt_fused(const float* __restrict__ X,
               const float* __restrict__ pos,
               const float* __restrict__ wqf, const float* __restrict__ bq_all,
               const float* __restrict__ wof, const float* __restrict__ bo_all,
               const float* __restrict__ w1f, const float* __restrict__ b1_all,
               const float* __restrict__ w2f, const float* __restrict__ b2_all,
               const float* __restrict__ g1_all, const float* __restrict__ be1_all,
               const float* __restrict__ g2_all, const float* __restrict__ be2_all,
               const float* __restrict__ hw, const float* __restrict__ hb,
               const short* __restrict__ wqb, const short* __restrict__ wob,
               const short* __restrict__ w1b, const short* __restrict__ w2b,
               float* __restrict__ out)
{
  __shared__ float xf[CW * XFS];        // fp32 residual stream
  __shared__ short xb[CW * 256];        // bf16 x (swizzled)
  __shared__ short qb[CW * 256];        // q -> attention output o (swizzled)
  __shared__ short kb[CW * 256];        // k -> FFN hidden chunk (swizzled)
  __shared__ short vtb[CH][32][40];     // v^T per head: [h][dh][tok]
  __shared__ short pb[CH][CW][40];      // softmax probs: [h][q][tok]

  const int tid = threadIdx.x;
  const int wave = tid >> 6;            // 0..15
  const int lane = tid & 63;
  const int lo = lane & 15;
  const int rb4 = (lane >> 4) << 2;     // C-layout row base
  const int k8 = (lane >> 4) << 3;      // A/B-frag k base

  const int blk = blockIdx.x;
  const int bb = blk >> 9;
  const int ss = blk & (CS - 1);

  // ---- Phase 0: build window (slot r = token clip(s-r,0)) + pos embed ----
  {
    int r = tid >> 5;                   // 0..31
    int c0 = (tid & 31) << 3;           // 8 floats each
    int src = ss - r; if (src < 0) src = 0;
    const float* Xr = X + ((size_t)(bb * CS + src)) * CD + c0;
    const float* Pr = pos + (size_t)r * CD + c0;
    f32x4 x0 = *(const f32x4*)(Xr);
    f32x4 x1 = *(const f32x4*)(Xr + 4);
    f32x4 p0 = *(const f32x4*)(Pr);
    f32x4 p1 = *(const f32x4*)(Pr + 4);
    bf16x8 pk;
#pragma unroll
    for (int j = 0; j < 4; ++j) {
      float v = x0[j] + p0[j];
      xf[r * XFS + c0 + j] = v;
      pk[j] = f2bf(v);
    }
#pragma unroll
    for (int j = 0; j < 4; ++j) {
      float v = x1[j] + p1[j];
      xf[r * XFS + c0 + 4 + j] = v;
      pk[4 + j] = f2bf(v);
    }
    *(bf16x8*)&xb[swz8(r, c0)] = pk;
  }
  __syncthreads();

  const float scale = 0.17677669529663687f;  // 1/sqrt(32)

  auto lnorm = [&](const float* g, const float* be) {
    int r = tid >> 5;                   // row 0..31
    int p = tid & 31;                   // 32 threads per row
    float* xr = xf + r * XFS;
    float s1 = 0.f, s2 = 0.f;
#pragma unroll
    for (int i = 0; i < 8; ++i) { float v = xr[p + (i << 5)]; s1 += v; s2 += v * v; }
#pragma unroll
    for (int d = 1; d < 32; d <<= 1) { s1 += __shfl_xor(s1, d); s2 += __shfl_xor(s2, d); }
    float mu = s1 * (1.f / 256.f);
    float var = s2 * (1.f / 256.f) - mu * mu;
    float rs = rsqrtf(var + 1e-5f);
#pragma unroll
    for (int i = 0; i < 4; ++i) {
      int c = (p << 1) + (i << 6);
      float v0 = (xr[c] - mu) * rs * g[c] + be[c];
      float v1 = (xr[c + 1] - mu) * rs * g[c + 1] + be[c + 1];
      xr[c] = v0;
      xr[c + 1] = v1;
      uint32_t pk2 = (uint32_t)(uint16_t)f2bf(v0) | ((uint32_t)(uint16_t)f2bf(v1) << 16);
      *(uint32_t*)&xb[swzi(r, c)] = pk2;
    }
  };

#pragma unroll 1
  for (int l = 0; l < CL; ++l) {
    // ================= QKV projection: [32,256] x [768,256]^T =================
    {
      const short* wb = wqb + (size_t)l * 768 * 256;
      const float* wf = wqf + (size_t)l * 768 * 256;
      const float* bias = bq_all + l * 768;
#pragma unroll 1
      for (int tp = 0; tp < 3; ++tp) {
        int n0 = wave * 48 + tp * 16;
        f32x4 c0 = {0.f,0.f,0.f,0.f}, c1 = c0;
#pragma unroll 4
        for (int kk = 0; kk < 8; ++kk) {
          bf16x8 a0 = *(const bf16x8*)&xb[swz8(lo, kk * 32 + k8)];
          bf16x8 a1 = *(const bf16x8*)&xb[swz8(16 + lo, kk * 32 + k8)];
          bf16x8 b0 = ldB<USEWS>(wb, wf, 256, n0, kk * 32, lane);
          c0 = mfma16(a0, b0, c0);
          c1 = mfma16(a1, b0, c1);
        }
        int col = n0 + lo;
        float bv = bias[col];
#pragma unroll
        for (int j = 0; j < 4; ++j) {
          float v0 = c0[j] + bv;
          float v1 = c1[j] + bv;
          int r0 = rb4 + j, r1 = rb4 + j + 16;
          if (n0 < 256) {               // q (pre-scaled)
            qb[swzi(r0, col)] = f2bf(v0 * scale);
            qb[swzi(r1, col)] = f2bf(v1 * scale);
          } else if (n0 < 512) {        // k
            kb[swzi(r0, col - 256)] = f2bf(v0);
            kb[swzi(r1, col - 256)] = f2bf(v1);
          } else {                      // v, transposed per head
            int h = (col - 512) >> 5, dh = (col - 512) & 31;
            vtb[h][dh][r0] = f2bf(v0);
            vtb[h][dh][r1] = f2bf(v1);
          }
        }
      }
    }
    __syncthreads();

    // ================= attention: (head, m-tile) = (wave>>1, wave&1) =================
    {
      int h = wave >> 1;
      int mt = wave & 1;
      int hc = h * 32;
      bf16x8 aq = *(const bf16x8*)&qb[swz8(mt * 16 + lo, hc + k8)];
      f32x4 sc[2];
#pragma unroll
      for (int nt = 0; nt < 2; ++nt) {
        bf16x8 bk = *(const bf16x8*)&kb[swz8(nt * 16 + lo, hc + k8)];
        f32x4 z = {0.f,0.f,0.f,0.f};
        sc[nt] = mfma16(aq, bk, z);
      }
#pragma unroll
      for (int j = 0; j < 4; ++j) {
        float v0 = sc[0][j], v1 = sc[1][j];
        float m = fmaxf(v0, v1);
#pragma unroll
        for (int d = 1; d < 16; d <<= 1) m = fmaxf(m, __shfl_xor(m, d));
        float p0 = __expf(v0 - m), p1 = __expf(v1 - m);
        float sm = p0 + p1;
#pragma unroll
        for (int d = 1; d < 16; d <<= 1) sm += __shfl_xor(sm, d);
        float inv = 1.0f / sm;
        int row = mt * 16 + rb4 + j;
        pb[h][row][lo]      = f2bf(p0 * inv);
        pb[h][row][16 + lo] = f2bf(p1 * inv);
      }
      asm volatile("s_waitcnt lgkmcnt(0)" ::: "memory");
      __builtin_amdgcn_sched_barrier(0);
      // PV: o[q][dh] = P @ v
      bf16x8 ap = *(const bf16x8*)&pb[h][mt * 16 + lo][k8];
#pragma unroll
      for (int dt = 0; dt < 2; ++dt) {
        bf16x8 bv = *(const bf16x8*)&vtb[h][dt * 16 + lo][k8];
        f32x4 z = {0.f,0.f,0.f,0.f};
        f32x4 o = mfma16(ap, bv, z);
#pragma unroll
        for (int j = 0; j < 4; ++j)
          qb[swzi(mt * 16 + rb4 + j, hc + dt * 16 + lo)] = f2bf(o[j]);
      }
    }
    __syncthreads();

    // ================= output projection + residual =================
    {
      const short* wb = wob + (size_t)l * 256 * 256;
      const float* wf = wof + (size_t)l * 256 * 256;
      const float* bias = bo_all + l * 256;
      int n0 = wave * 16;
      f32x4 c0 = {0.f,0.f,0.f,0.f}, c1 = c0;
#pragma unroll 4
      for (int kk = 0; kk < 8; ++kk) {
        bf16x8 a0 = *(const bf16x8*)&qb[swz8(lo, kk * 32 + k8)];
        bf16x8 a1 = *(const bf16x8*)&qb[swz8(16 + lo, kk * 32 + k8)];
        bf16x8 b0 = ldB<USEWS>(wb, wf, 256, n0, kk * 32, lane);
        c0 = mfma16(a0, b0, c0);
        c1 = mfma16(a1, b0, c1);
      }
      int col = n0 + lo;
      float bv = bias[col];
#pragma unroll
      for (int j = 0; j < 4; ++j) {
        xf[(rb4 + j) * XFS + col]      += c0[j] + bv;
        xf[(rb4 + j + 16) * XFS + col] += c1[j] + bv;
      }
    }
    __syncthreads();
    lnorm(g1_all + l * 256, be1_all + l * 256);
    __syncthreads();

    // ================= FFN: relu(x W1^T) W2^T, 4 chunks of 256 =================
    {
      const short* w1bl = w1b + (size_t)l * 1024 * 256;
      const float* w1fl = w1f + (size_t)l * 1024 * 256;
      const float* bias1 = b1_all + l * 1024;
      const short* w2bl = w2b + (size_t)l * 256 * 1024;
      const float* w2fl = w2f + (size_t)l * 256 * 1024;
      f32x4 fa0 = {0.f,0.f,0.f,0.f}, fa1 = fa0;
      const int n0 = wave * 16;

#pragma unroll 1
      for (int ch = 0; ch < 4; ++ch) {
        int ng = ch * 256 + n0;
        f32x4 c0 = {0.f,0.f,0.f,0.f}, c1 = c0;
#pragma unroll 4
        for (int kk = 0; kk < 8; ++kk) {
          bf16x8 a0 = *(const bf16x8*)&xb[swz8(lo, kk * 32 + k8)];
          bf16x8 a1 = *(const bf16x8*)&xb[swz8(16 + lo, kk * 32 + k8)];
          bf16x8 b0 = ldB<USEWS>(w1bl, w1fl, 256, ng, kk * 32, lane);
          c0 = mfma16(a0, b0, c0);
          c1 = mfma16(a1, b0, c1);
        }
        int colL = n0 + lo;
        float bv = bias1[ng + lo];
#pragma unroll
        for (int j = 0; j < 4; ++j) {
          kb[swzi(rb4 + j, colL)]      = f2bf(fmaxf(c0[j] + bv, 0.f));
          kb[swzi(rb4 + j + 16, colL)] = f2bf(fmaxf(c1[j] + bv, 0.f));
        }
        __syncthreads();
        // FFN2 partial over this K-chunk
#pragma unroll 4
        for (int kk = 0; kk < 8; ++kk) {
          bf16x8 h0 = *(const bf16x8*)&kb[swz8(lo, kk * 32 + k8)];
          bf16x8 h1 = *(const bf16x8*)&kb[swz8(16 + lo, kk * 32 + k8)];
          bf16x8 b0 = ldB<USEWS>(w2bl, w2fl, 1024, n0, ch * 256 + kk * 32, lane);
          fa0 = mfma16(h0, b0, fa0);
          fa1 = mfma16(h1, b0, fa1);
        }
        __syncthreads();
      }
      // FFN2 epilogue: bias + residual
      const float* bias2 = b2_all + l * 256;
      int col = n0 + lo;
      float bv = bias2[col];
#pragma unroll
      for (int j = 0; j < 4; ++j) {
        xf[(rb4 + j) * XFS + col]      += fa0[j] + bv;
        xf[(rb4 + j + 16) * XFS + col] += fa1[j] + bv;
      }
    }
    __syncthreads();
    lnorm(g2_all + l * 256, be2_all + l * 256);
    __syncthreads();
  }

  // ================= head: logits = x[slot 31] @ head_w^T + head_b =================
  {
    int c = tid >> 5;        // 0..31 output
    int p = tid & 31;        // 32-way K split
    float sum = 0.f;
#pragma unroll
    for (int i = 0; i < 8; ++i) {
      int k = p + (i << 5);
      sum += xf[31 * XFS + k] * hw[c * 256 + k];
    }
#pragma unroll
    for (int d = 1; d < 32; d <<= 1) sum += __shfl_xor(sum, d);
    if (p == 0) out[(size_t)blk * 32 + c] = sum + hb[c];
  }
}

extern "C" void kernel_launch(void* const* d_in, const int* in_sizes, int n_in,
                              void* d_out, int out_size, void* d_ws, size_t ws_size,
                              hipStream_t stream) {
  const float* X    = (const float*)d_in[0];
  const float* pos  = (const float*)d_in[3];
  const float* wq   = (const float*)d_in[4];
  const float* bq   = (const float*)d_in[5];
  const float* wo   = (const float*)d_in[6];
  const float* bo   = (const float*)d_in[7];
  const float* w1   = (const float*)d_in[8];
  const float* b1   = (const float*)d_in[9];
  const float* w2   = (const float*)d_in[10];
  const float* b2   = (const float*)d_in[11];
  const float* g1   = (const float*)d_in[12];
  const float* be1  = (const float*)d_in[13];
  const float* g2   = (const float*)d_in[14];
  const float* be2  = (const float*)d_in[15];
  const float* hw   = (const float*)d_in[16];
  const float* hb   = (const float*)d_in[17];
  float* out = (float*)d_out;

  const size_t nq = (size_t)CL * 768 * 256;
  const size_t no = (size_t)CL * 256 * 256;
  const size_t n1 = (size_t)CL * 1024 * 256;
  const size_t n2 = (size_t)CL * 256 * 1024;
  const size_t need = (nq + no + n1 + n2) * sizeof(short);

  short* wsq = (short*)d_ws;
  short* wso = wsq + nq;
  short* ws1 = wso + no;
  short* ws2 = ws1 + n1;

  const int nblk = 4 * 512;

  if (ws_size >= need) {
    cvt_bf16<<<1024, 256, 0, stream>>>(wq, wsq, (int)nq);
    cvt_bf16<<<1024, 256, 0, stream>>>(wo, wso, (int)no);
    cvt_bf16<<<1024, 256, 0, stream>>>(w1, ws1, (int)n1);
    cvt_bf16<<<1024, 256, 0, stream>>>(w2, ws2, (int)n2);
    swt_fused<1><<<nblk, 1024, 0, stream>>>(X, pos, wq, bq, wo, bo, w1, b1, w2, b2,
                                            g1, be1, g2, be2, hw, hb,
                                            wsq, wso, ws1, ws2, out);
  } else {
    swt_fused<0><<<nblk, 1024, 0, stream>>>(X, pos, wq, bq, wo, bo, w1, b1, w2, b2,
                                            g1, be1, g2, be2, hw, hb,
                                            nullptr, nullptr, nullptr, nullptr, out);
  }
}